// Round 3
// baseline (1825.312 us; speedup 1.0000x reference)
//
#include <hip/hip_runtime.h>

#define NN 50000
#define NPAD 50048           // padded to multiple of 64 rows
#define EE 800000
#define RR 8
#define NR (NN * RR)         // 400000 (dst,rel) segments
#define KK 1152              // 128 (root) + 8*128 (relations)
#define KREL 1024            // relation-only K columns

typedef __attribute__((ext_vector_type(8))) short bf16x8;
typedef __attribute__((ext_vector_type(4))) float f32x4;

__device__ __forceinline__ unsigned short f2bf(float f) {
    unsigned u = __builtin_bit_cast(unsigned, f);
    u = (u + 0x7FFF + ((u >> 16) & 1)) >> 16;   // RNE
    return (unsigned short)u;
}
__device__ __forceinline__ float bf2f(unsigned short s) {
    return __builtin_bit_cast(float, (unsigned)s << 16);
}

#define GLDS16(g, l) __builtin_amdgcn_global_load_lds( \
    (const __attribute__((address_space(1))) void*)(g), \
    (__attribute__((address_space(3))) void*)(l), 16, 0, 0)

// ---------------- graph preprocessing ----------------
__global__ void zero_i32(int* __restrict__ p, int n) {
    int i = blockIdx.x * blockDim.x + threadIdx.x;
    if (i < n) p[i] = 0;
}

__global__ void count_deg(const int* __restrict__ dst, const int* __restrict__ et,
                          int* __restrict__ deg) {
    int e = blockIdx.x * blockDim.x + threadIdx.x;
    if (e < EE) atomicAdd(&deg[dst[e] * RR + et[e]], 1);
}

// exclusive scan over n ints: 1024 per block
__global__ __launch_bounds__(256) void scan1(const int* __restrict__ in, int* __restrict__ out,
                                             int* __restrict__ bsum, int n) {
    __shared__ int sh[256];
    int t = threadIdx.x;
    int base = blockIdx.x * 1024 + t * 4;
    int v[4]; int s = 0;
    #pragma unroll
    for (int i = 0; i < 4; ++i) { int idx = base + i; v[i] = (idx < n) ? in[idx] : 0; s += v[i]; }
    sh[t] = s; __syncthreads();
    for (int off = 1; off < 256; off <<= 1) {
        int x = (t >= off) ? sh[t - off] : 0; __syncthreads();
        if (t >= off) sh[t] += x; __syncthreads();
    }
    if (t == 255) bsum[blockIdx.x] = sh[255];
    int run = sh[t] - s;
    #pragma unroll
    for (int i = 0; i < 4; ++i) { int idx = base + i; if (idx < n) out[idx] = run; run += v[i]; }
}

__global__ __launch_bounds__(256) void scan2(int* __restrict__ bsum, int nb) {
    __shared__ int sh[256];
    int t = threadIdx.x; int carry = 0;
    for (int base = 0; base < nb; base += 256) {
        int idx = base + t;
        int v = (idx < nb) ? bsum[idx] : 0;
        sh[t] = v; __syncthreads();
        for (int off = 1; off < 256; off <<= 1) {
            int x = (t >= off) ? sh[t - off] : 0; __syncthreads();
            if (t >= off) sh[t] += x; __syncthreads();
        }
        int incl = sh[t];
        int total = sh[255];
        if (idx < nb) bsum[idx] = carry + incl - v;   // exclusive
        carry += total;
        __syncthreads();
    }
}

__global__ __launch_bounds__(256) void scan3(int* __restrict__ out, const int* __restrict__ bsum, int n) {
    int base = blockIdx.x * 1024 + threadIdx.x * 4;
    int add = bsum[blockIdx.x];
    #pragma unroll
    for (int i = 0; i < 4; ++i) { int idx = base + i; if (idx < n) out[idx] += add; }
}

__global__ void set_last(int* __restrict__ segStart) {
    segStart[NR] = EE;
}

// sortedSrcR[pos] = src | (r << 20)
__global__ void scatter_edges(const int* __restrict__ src, const int* __restrict__ dst,
                              const int* __restrict__ et, const int* __restrict__ segStart,
                              int* __restrict__ cursor, int* __restrict__ ssr) {
    int e = blockIdx.x * blockDim.x + threadIdx.x;
    if (e >= EE) return;
    int r = et[e];
    int seg = dst[e] * RR + r;
    int pos = segStart[seg] + atomicAdd(&cursor[seg], 1);
    ssr[pos] = src[e] | (r << 20);
}

// ---------------- x -> bf16 (pad rows zeroed) ----------------
__global__ __launch_bounds__(256) void xcvt(const float* __restrict__ x,
                                            unsigned short* __restrict__ xbf) {
    size_t i = ((size_t)blockIdx.x * 256 + threadIdx.x) * 4;
    if (i >= (size_t)NPAD * 128) return;
    unsigned short o[4];
    if (i < (size_t)NN * 128) {
        float4 v = *reinterpret_cast<const float4*>(x + i);
        o[0] = f2bf(v.x); o[1] = f2bf(v.y); o[2] = f2bf(v.z); o[3] = f2bf(v.w);
    } else {
        o[0] = o[1] = o[2] = o[3] = 0;
    }
    unsigned lo = (unsigned)o[0] | ((unsigned)o[1] << 16);
    unsigned hi = (unsigned)o[2] | ((unsigned)o[3] << 16);
    *reinterpret_cast<uint2*>(xbf + i) = make_uint2(lo, hi);
}

// ---------------- weight layout: Bt[col][k] = Bmat[k][col], bf16 ----------------
__global__ void build_bt(const float* __restrict__ W, const float* __restrict__ root,
                         unsigned short* __restrict__ Bt) {
    int i = blockIdx.x * blockDim.x + threadIdx.x;
    if (i >= 128 * KK) return;
    int col = i / KK, k = i % KK;
    float v;
    if (k < 128) v = root[k * 128 + col];
    else {
        int r = (k - 128) >> 7, kp = (k - 128) & 127;
        v = W[((size_t)r * 128 + kp) * 128 + col];
    }
    Bt[i] = f2bf(v);
}

// ---------------- aggregation v2: one wave per node, LDS f32 accumulators ----------------
// Arel[n][r*128+h] = mean over r-segment of hin[src][h]
__global__ __launch_bounds__(256) void aggregate2(
    const unsigned short* __restrict__ hin,   // [NPAD][128] bf16
    const int* __restrict__ segStart,         // [NR+1]
    const int* __restrict__ ssr,              // [EE] src | (r<<20)
    unsigned short* __restrict__ Arel)        // [NPAD][1024] bf16
{
    __shared__ float accf[4][1024];
    const int w = threadIdx.x >> 6, l = threadIdx.x & 63;
    float* acc = accf[w];
    const int n = blockIdx.x * 4 + w;

    #pragma unroll
    for (int i = 0; i < 8; ++i)
        *reinterpret_cast<float2*>(&acc[i * 128 + 2 * l]) = make_float2(0.f, 0.f);

    if (n < NN) {
        const int base = n * 8;
        const int s0 = segStart[base];
        const int s8 = segStart[base + 8];
        int e = s0;
        for (; e + 4 <= s8; e += 4) {
            int p0 = ssr[e], p1 = ssr[e + 1], p2 = ssr[e + 2], p3 = ssr[e + 3];
            unsigned f0 = *reinterpret_cast<const unsigned*>(hin + (((size_t)(p0 & 0xFFFFF)) << 7) + 2 * l);
            unsigned f1 = *reinterpret_cast<const unsigned*>(hin + (((size_t)(p1 & 0xFFFFF)) << 7) + 2 * l);
            unsigned f2 = *reinterpret_cast<const unsigned*>(hin + (((size_t)(p2 & 0xFFFFF)) << 7) + 2 * l);
            unsigned f3 = *reinterpret_cast<const unsigned*>(hin + (((size_t)(p3 & 0xFFFFF)) << 7) + 2 * l);
            atomicAdd(&acc[((p0 >> 20) << 7) + 2 * l],     bf2f((unsigned short)(f0 & 0xFFFF)));
            atomicAdd(&acc[((p0 >> 20) << 7) + 2 * l + 1], bf2f((unsigned short)(f0 >> 16)));
            atomicAdd(&acc[((p1 >> 20) << 7) + 2 * l],     bf2f((unsigned short)(f1 & 0xFFFF)));
            atomicAdd(&acc[((p1 >> 20) << 7) + 2 * l + 1], bf2f((unsigned short)(f1 >> 16)));
            atomicAdd(&acc[((p2 >> 20) << 7) + 2 * l],     bf2f((unsigned short)(f2 & 0xFFFF)));
            atomicAdd(&acc[((p2 >> 20) << 7) + 2 * l + 1], bf2f((unsigned short)(f2 >> 16)));
            atomicAdd(&acc[((p3 >> 20) << 7) + 2 * l],     bf2f((unsigned short)(f3 & 0xFFFF)));
            atomicAdd(&acc[((p3 >> 20) << 7) + 2 * l + 1], bf2f((unsigned short)(f3 >> 16)));
        }
        for (; e < s8; ++e) {
            int p = ssr[e];
            unsigned f = *reinterpret_cast<const unsigned*>(hin + (((size_t)(p & 0xFFFFF)) << 7) + 2 * l);
            atomicAdd(&acc[((p >> 20) << 7) + 2 * l],     bf2f((unsigned short)(f & 0xFFFF)));
            atomicAdd(&acc[((p >> 20) << 7) + 2 * l + 1], bf2f((unsigned short)(f >> 16)));
        }
        #pragma unroll
        for (int r = 0; r < 8; ++r) {
            int d = segStart[base + r + 1] - segStart[base + r];
            float inv = (d > 0) ? 1.f / (float)d : 0.f;
            float2 v = *reinterpret_cast<float2*>(&acc[r * 128 + 2 * l]);
            unsigned pack = (unsigned)f2bf(v.x * inv) | ((unsigned)f2bf(v.y * inv) << 16);
            *reinterpret_cast<unsigned*>(Arel + (size_t)n * KREL + r * 128 + 2 * l) = pack;
        }
    } else if (n < NPAD) {
        #pragma unroll
        for (int r = 0; r < 8; ++r)
            *reinterpret_cast<unsigned*>(Arel + (size_t)n * KREL + r * 128 + 2 * l) = 0u;
    }
}

// ---------------- MFMA GEMM: C = relu([hin | Arel] @ B + bias) -> bf16 ----------------
// BM=64, 4 waves; wave w: rows 0..63, cols w*32..w*32+31; double-buffered LDS
__global__ __launch_bounds__(256) void mfma_gemm(
    const unsigned short* __restrict__ Aroot,   // [NPAD][128] (hin)
    const unsigned short* __restrict__ Arel,    // [NPAD][1024]
    const unsigned short* __restrict__ Bt,      // [128][1152] (Bt[col][k])
    const float* __restrict__ bias,             // [128]
    unsigned short* __restrict__ Cout)          // [NPAD][128] bf16
{
    __shared__ alignas(16) unsigned short As[2][64 * 64];
    __shared__ alignas(16) unsigned short Bs[2][128 * 64];
    const int tid = threadIdx.x;
    const int w = tid >> 6, lane = tid & 63;
    const int l15 = lane & 15, lhi = lane >> 4;
    const int row0 = blockIdx.x * 64;

    f32x4 acc[4][2];
    #pragma unroll
    for (int m = 0; m < 4; ++m)
        #pragma unroll
        for (int n = 0; n < 2; ++n) acc[m][n] = (f32x4)(0.f);

    auto stage = [&](int b, int kt) {
        #pragma unroll
        for (int i = 0; i < 2; ++i) {
            int q = w * 128 + i * 64 + lane;          // chunk id 0..511
            int row = q >> 3, c = q & 7;
            const unsigned short* g;
            if (kt < 2) g = Aroot + (size_t)(row0 + row) * 128 + kt * 64 + ((c ^ (row & 7)) * 8);
            else        g = Arel  + (size_t)(row0 + row) * KREL + (kt - 2) * 64 + ((c ^ (row & 7)) * 8);
            GLDS16(g, &As[b][(w * 128 + i * 64) * 8]);
        }
        #pragma unroll
        for (int i = 0; i < 4; ++i) {
            int q = w * 256 + i * 64 + lane;          // chunk id 0..1023
            int col = q >> 3, c = q & 7;
            const unsigned short* g = Bt + (size_t)col * KK + kt * 64 + ((c ^ (col & 7)) * 8);
            GLDS16(g, &Bs[b][(w * 256 + i * 64) * 8]);
        }
    };

    stage(0, 0);
    __syncthreads();
    for (int kt = 0; kt < KK / 64; ++kt) {
        const int cur = kt & 1;
        if (kt < KK / 64 - 1) stage(cur ^ 1, kt + 1);   // issue next-tile loads, overlap compute
        #pragma unroll
        for (int j = 0; j < 2; ++j) {
            const int clog = j * 4 + lhi;
            bf16x8 af[4], bfr[2];
            #pragma unroll
            for (int m = 0; m < 4; ++m) {
                int row = m * 16 + l15;
                int ch = clog ^ (row & 7);
                af[m] = *reinterpret_cast<const bf16x8*>(&As[cur][row * 64 + ch * 8]);
            }
            #pragma unroll
            for (int n = 0; n < 2; ++n) {
                int col = w * 32 + n * 16 + l15;
                int ch = clog ^ (col & 7);
                bfr[n] = *reinterpret_cast<const bf16x8*>(&Bs[cur][col * 64 + ch * 8]);
            }
            #pragma unroll
            for (int m = 0; m < 4; ++m)
                #pragma unroll
                for (int n = 0; n < 2; ++n)
                    acc[m][n] = __builtin_amdgcn_mfma_f32_16x16x32_bf16(af[m], bfr[n], acc[m][n], 0, 0, 0);
        }
        __syncthreads();   // drains vmcnt(0): tile kt+1 staged, buffers swap
    }
    #pragma unroll
    for (int n = 0; n < 2; ++n) {
        int col = w * 32 + n * 16 + l15;
        float bv = bias[col];
        #pragma unroll
        for (int m = 0; m < 4; ++m) {
            #pragma unroll
            for (int r = 0; r < 4; ++r) {
                int grow = row0 + m * 16 + lhi * 4 + r;
                float v = fmaxf(acc[m][n][r] + bv, 0.f);
                Cout[(size_t)grow * 128 + col] = f2bf(v);
            }
        }
    }
}

// ---------------- final FC ----------------
__global__ __launch_bounds__(256) void final_fc(
    const unsigned short* __restrict__ h, const float* __restrict__ fcw,
    const float* __restrict__ fcb, float* __restrict__ out)
{
    int wid  = (int)((blockIdx.x * 256 + threadIdx.x) >> 6);
    int lane = threadIdx.x & 63;
    if (wid >= NN) return;
    float v = bf2f(h[(size_t)wid * 128 + lane]) * fcw[lane]
            + bf2f(h[(size_t)wid * 128 + 64 + lane]) * fcw[64 + lane];
    #pragma unroll
    for (int off = 32; off > 0; off >>= 1) v += __shfl_down(v, off);
    if (lane == 0) out[wid] = v + fcb[0];
}

extern "C" void kernel_launch(void* const* d_in, const int* in_sizes, int n_in,
                              void* d_out, int out_size, void* d_ws, size_t ws_size,
                              hipStream_t stream) {
    const float* x     = (const float*)d_in[0];
    const int*   ei    = (const int*)d_in[1];
    const int*   etype = (const int*)d_in[2];
    const float* W[3]    = {(const float*)d_in[3], (const float*)d_in[6], (const float*)d_in[9]};
    const float* root[3] = {(const float*)d_in[4], (const float*)d_in[7], (const float*)d_in[10]};
    const float* bias[3] = {(const float*)d_in[5], (const float*)d_in[8], (const float*)d_in[11]};
    const float* fcw = (const float*)d_in[12];
    const float* fcb = (const float*)d_in[13];
    const int* src = ei;
    const int* dst = ei + EE;

    char* ws = (char*)d_ws;
    auto alloc = [&](size_t bytes) { char* p = ws; ws += (bytes + 255) & ~(size_t)255; return p; };
    int* deg       = (int*)alloc(NR * sizeof(int));
    int* cursor    = (int*)alloc(NR * sizeof(int));
    int* segStart  = (int*)alloc((NR + 2) * sizeof(int));
    int* bsum      = (int*)alloc(512 * sizeof(int));
    int* ssr       = (int*)alloc(EE * sizeof(int));
    unsigned short* Btg  = (unsigned short*)alloc((size_t)3 * 128 * KK * sizeof(short));
    unsigned short* xbf  = (unsigned short*)alloc((size_t)NPAD * 128 * sizeof(short));
    unsigned short* h1   = (unsigned short*)alloc((size_t)NPAD * 128 * sizeof(short));
    unsigned short* h2   = (unsigned short*)alloc((size_t)NPAD * 128 * sizeof(short));
    unsigned short* Arel = (unsigned short*)alloc((size_t)NPAD * KREL * sizeof(short));

    // --- graph preprocessing ---
    zero_i32<<<(2 * NR + 255) / 256, 256, 0, stream>>>(deg, 2 * NR);   // deg + cursor contiguous
    count_deg<<<(EE + 255) / 256, 256, 0, stream>>>(dst, etype, deg);
    const int nScanBlk = (NR + 1023) / 1024;   // 391
    scan1<<<nScanBlk, 256, 0, stream>>>(deg, segStart, bsum, NR);
    scan2<<<1, 256, 0, stream>>>(bsum, nScanBlk);
    scan3<<<nScanBlk, 256, 0, stream>>>(segStart, bsum, NR);
    set_last<<<1, 1, 0, stream>>>(segStart);
    scatter_edges<<<(EE + 255) / 256, 256, 0, stream>>>(src, dst, etype, segStart, cursor, ssr);

    // --- input conversion + weight panels ---
    xcvt<<<((NPAD * 128 / 4) + 255) / 256, 256, 0, stream>>>(x, xbf);
    const int btThreads = 128 * KK;
    for (int l = 0; l < 3; ++l)
        build_bt<<<(btThreads + 255) / 256, 256, 0, stream>>>(W[l], root[l], Btg + (size_t)l * 128 * KK);

    const int gemmGrid = NPAD / 64;      // 782
    const int aggGrid  = NPAD / 4;       // 12512
    const unsigned short* hin = xbf;
    unsigned short* houts[3] = {h1, h2, h1};
    for (int l = 0; l < 3; ++l) {
        aggregate2<<<aggGrid, 256, 0, stream>>>(hin, segStart, ssr, Arel);
        mfma_gemm<<<gemmGrid, 256, 0, stream>>>(hin, Arel, Btg + (size_t)l * 128 * KK, bias[l], houts[l]);
        hin = houts[l];
    }

    final_fc<<<(NN * 64 + 255) / 256, 256, 0, stream>>>(h1, fcw, fcb, (float*)d_out);
}

// Round 4
// 1081.347 us; speedup vs baseline: 1.6880x; 1.6880x over previous
//
#include <hip/hip_runtime.h>

#define NN 50000
#define NPAD 50048           // padded to multiple of 64 rows
#define EE 800000
#define RR 8
#define NR (NN * RR)         // 400000 (dst,rel) segments
#define KK 1152              // 128 (root) + 8*128 (relations)

typedef __attribute__((ext_vector_type(8))) short bf16x8;
typedef __attribute__((ext_vector_type(4))) float f32x4;

__device__ __forceinline__ unsigned short f2bf(float f) {
    unsigned u = __builtin_bit_cast(unsigned, f);
    u = (u + 0x7FFF + ((u >> 16) & 1)) >> 16;   // RNE
    return (unsigned short)u;
}
__device__ __forceinline__ float bf2f(unsigned short s) {
    return __builtin_bit_cast(float, (unsigned)s << 16);
}

#define GLDS16(g, l) __builtin_amdgcn_global_load_lds( \
    (const __attribute__((address_space(1))) void*)(g), \
    (__attribute__((address_space(3))) void*)(l), 16, 0, 0)

// ---------------- graph preprocessing ----------------
__global__ void zero_i32(int* __restrict__ p, int n) {
    int i = blockIdx.x * blockDim.x + threadIdx.x;
    if (i < n) p[i] = 0;
}

__global__ void count_deg(const int* __restrict__ dst, const int* __restrict__ et,
                          int* __restrict__ deg) {
    int e = blockIdx.x * blockDim.x + threadIdx.x;
    if (e < EE) atomicAdd(&deg[dst[e] * RR + et[e]], 1);
}

// exclusive scan over n ints: 1024 per block
__global__ __launch_bounds__(256) void scan1(const int* __restrict__ in, int* __restrict__ out,
                                             int* __restrict__ bsum, int n) {
    __shared__ int sh[256];
    int t = threadIdx.x;
    int base = blockIdx.x * 1024 + t * 4;
    int v[4]; int s = 0;
    #pragma unroll
    for (int i = 0; i < 4; ++i) { int idx = base + i; v[i] = (idx < n) ? in[idx] : 0; s += v[i]; }
    sh[t] = s; __syncthreads();
    for (int off = 1; off < 256; off <<= 1) {
        int x = (t >= off) ? sh[t - off] : 0; __syncthreads();
        if (t >= off) sh[t] += x; __syncthreads();
    }
    if (t == 255) bsum[blockIdx.x] = sh[255];
    int run = sh[t] - s;
    #pragma unroll
    for (int i = 0; i < 4; ++i) { int idx = base + i; if (idx < n) out[idx] = run; run += v[i]; }
}

__global__ __launch_bounds__(256) void scan2(int* __restrict__ bsum, int nb) {
    __shared__ int sh[256];
    int t = threadIdx.x; int carry = 0;
    for (int base = 0; base < nb; base += 256) {
        int idx = base + t;
        int v = (idx < nb) ? bsum[idx] : 0;
        sh[t] = v; __syncthreads();
        for (int off = 1; off < 256; off <<= 1) {
            int x = (t >= off) ? sh[t - off] : 0; __syncthreads();
            if (t >= off) sh[t] += x; __syncthreads();
        }
        int incl = sh[t];
        int total = sh[255];
        if (idx < nb) bsum[idx] = carry + incl - v;   // exclusive
        carry += total;
        __syncthreads();
    }
}

__global__ __launch_bounds__(256) void scan3(int* __restrict__ out, const int* __restrict__ bsum, int n) {
    int base = blockIdx.x * 1024 + threadIdx.x * 4;
    int add = bsum[blockIdx.x];
    #pragma unroll
    for (int i = 0; i < 4; ++i) { int idx = base + i; if (idx < n) out[idx] += add; }
}

__global__ void set_last(int* __restrict__ segStart) {
    segStart[NR] = EE;
}

__global__ void scatter_edges(const int* __restrict__ src, const int* __restrict__ dst,
                              const int* __restrict__ et, const int* __restrict__ segStart,
                              int* __restrict__ cursor, int* __restrict__ ssr) {
    int e = blockIdx.x * blockDim.x + threadIdx.x;
    if (e >= EE) return;
    int seg = dst[e] * RR + et[e];
    int pos = segStart[seg] + atomicAdd(&cursor[seg], 1);
    ssr[pos] = src[e];
}

// ---------------- x -> bf16 (pad rows zeroed) ----------------
__global__ __launch_bounds__(256) void xcvt(const float* __restrict__ x,
                                            unsigned short* __restrict__ xbf) {
    size_t i = ((size_t)blockIdx.x * 256 + threadIdx.x) * 4;
    if (i >= (size_t)NPAD * 128) return;
    unsigned short o[4];
    if (i < (size_t)NN * 128) {
        float4 v = *reinterpret_cast<const float4*>(x + i);
        o[0] = f2bf(v.x); o[1] = f2bf(v.y); o[2] = f2bf(v.z); o[3] = f2bf(v.w);
    } else {
        o[0] = o[1] = o[2] = o[3] = 0;
    }
    unsigned lo = (unsigned)o[0] | ((unsigned)o[1] << 16);
    unsigned hi = (unsigned)o[2] | ((unsigned)o[3] << 16);
    *reinterpret_cast<uint2*>(xbf + i) = make_uint2(lo, hi);
}

// ---------------- weight layout: Bt[col][k] = Bmat[k][col], bf16 ----------------
__global__ void build_bt(const float* __restrict__ W, const float* __restrict__ root,
                         unsigned short* __restrict__ Bt) {
    int i = blockIdx.x * blockDim.x + threadIdx.x;
    if (i >= 128 * KK) return;
    int col = i / KK, k = i % KK;
    float v;
    if (k < 128) v = root[k * 128 + col];
    else {
        int r = (k - 128) >> 7, kp = (k - 128) & 127;
        v = W[((size_t)r * 128 + kp) * 128 + col];
    }
    Bt[i] = f2bf(v);
}

// ---------------- fused layer: C = relu([hin | seg-means(hin)] @ B + bias) ----------------
// BM=64, 4 waves; K-tiles of 64: kt 0..1 = root cols (global_load_lds from hin);
// kt 2..17 = relation (r=(kt-2)>>1, half=(kt-2)&1): each half-wave computes one
// node's segment mean directly into the swizzled LDS A-tile.
__global__ __launch_bounds__(256) void fused_layer(
    const unsigned short* __restrict__ hin,   // [NPAD][128] bf16
    const int* __restrict__ segStart,         // [NR+1]
    const int* __restrict__ ssr,              // [EE] sorted src ids
    const unsigned short* __restrict__ Bt,    // [128][1152] (Bt[col][k])
    const float* __restrict__ bias,           // [128]
    unsigned short* __restrict__ Cout)        // [NPAD][128] bf16
{
    __shared__ alignas(16) unsigned short As[2][64 * 64];
    __shared__ alignas(16) unsigned short Bs[2][128 * 64];
    __shared__ int segL[513];
    const int tid = threadIdx.x;
    const int w = tid >> 6, lane = tid & 63;
    const int l15 = lane & 15, lhi = lane >> 4;
    const int hw = lane >> 5;          // half-wave 0/1
    const int i2 = lane & 31;          // dword lane within half-wave (2 cols)
    const int row0 = blockIdx.x * 64;

    // segment bounds for this block's 64 nodes (clamped for pad nodes)
    for (int i = tid; i < 513; i += 256) {
        int gi = row0 * 8 + i;
        segL[i] = (gi <= NR) ? segStart[gi] : EE;
    }

    f32x4 acc[4][2];
    #pragma unroll
    for (int m = 0; m < 4; ++m)
        #pragma unroll
        for (int n = 0; n < 2; ++n) acc[m][n] = (f32x4)(0.f);

    auto stageB = [&](int b, int kt) {
        #pragma unroll
        for (int i = 0; i < 4; ++i) {
            int q = w * 256 + i * 64 + lane;          // chunk id 0..1023
            int col = q >> 3, c = q & 7;
            const unsigned short* g = Bt + (size_t)col * KK + kt * 64 + ((c ^ (col & 7)) * 8);
            GLDS16(g, &Bs[b][(w * 256 + i * 64) * 8]);
        }
    };
    auto stageAroot = [&](int b, int kt) {
        #pragma unroll
        for (int i = 0; i < 2; ++i) {
            int q = w * 128 + i * 64 + lane;          // chunk id 0..511
            int row = q >> 3, c = q & 7;
            const unsigned short* g = hin + (size_t)(row0 + row) * 128 + kt * 64 + ((c ^ (row & 7)) * 8);
            GLDS16(g, &As[b][(w * 128 + i * 64) * 8]);
        }
    };
    auto stageArel = [&](int b, int kt) {
        const int rr = (kt - 2) >> 1, half = (kt - 2) & 1;
        const unsigned short* hbase = hin + half * 64 + i2 * 2;
        for (int p = 0; p < 8; ++p) {
            int ln = w * 16 + p * 2 + hw;             // local row 0..63
            int s0 = segL[ln * 8 + rr], s1 = segL[ln * 8 + rr + 1];
            float a0x = 0.f, a0y = 0.f, a1x = 0.f, a1y = 0.f;
            int e = s0;
            for (; e + 2 <= s1; e += 2) {             // unroll-2: independent loads
                int sA = ssr[e], sB = ssr[e + 1];
                unsigned fA = *reinterpret_cast<const unsigned*>(hbase + ((size_t)sA << 7));
                unsigned fB = *reinterpret_cast<const unsigned*>(hbase + ((size_t)sB << 7));
                a0x += bf2f((unsigned short)(fA & 0xFFFF)); a0y += bf2f((unsigned short)(fA >> 16));
                a1x += bf2f((unsigned short)(fB & 0xFFFF)); a1y += bf2f((unsigned short)(fB >> 16));
            }
            if (e < s1) {
                int sA = ssr[e];
                unsigned fA = *reinterpret_cast<const unsigned*>(hbase + ((size_t)sA << 7));
                a0x += bf2f((unsigned short)(fA & 0xFFFF)); a0y += bf2f((unsigned short)(fA >> 16));
            }
            int d = s1 - s0;
            float inv = (d > 0) ? 1.f / (float)d : 0.f;
            unsigned pack = (unsigned)f2bf((a0x + a1x) * inv)
                          | ((unsigned)f2bf((a0y + a1y) * inv) << 16);
            // swizzled write: logical dword i2 of row ln -> chunk (i2>>2)^(ln&7)
            int ch = (i2 >> 2) ^ (ln & 7);
            *reinterpret_cast<unsigned*>(
                reinterpret_cast<char*>(&As[b][0]) + ln * 128 + ch * 16 + (i2 & 3) * 4) = pack;
        }
    };

    stageB(0, 0);
    stageAroot(0, 0);
    __syncthreads();
    for (int kt = 0; kt < KK / 64; ++kt) {
        const int cur = kt & 1;
        if (kt < KK / 64 - 1) {
            stageB(cur ^ 1, kt + 1);
            if (kt + 1 < 2) stageAroot(cur ^ 1, kt + 1);
            else            stageArel(cur ^ 1, kt + 1);
        }
        #pragma unroll
        for (int j = 0; j < 2; ++j) {
            const int clog = j * 4 + lhi;
            bf16x8 af[4], bfr[2];
            #pragma unroll
            for (int m = 0; m < 4; ++m) {
                int row = m * 16 + l15;
                int ch = clog ^ (row & 7);
                af[m] = *reinterpret_cast<const bf16x8*>(&As[cur][row * 64 + ch * 8]);
            }
            #pragma unroll
            for (int n = 0; n < 2; ++n) {
                int col = w * 32 + n * 16 + l15;
                int ch = clog ^ (col & 7);
                bfr[n] = *reinterpret_cast<const bf16x8*>(&Bs[cur][col * 64 + ch * 8]);
            }
            #pragma unroll
            for (int m = 0; m < 4; ++m)
                #pragma unroll
                for (int n = 0; n < 2; ++n)
                    acc[m][n] = __builtin_amdgcn_mfma_f32_16x16x32_bf16(af[m], bfr[n], acc[m][n], 0, 0, 0);
        }
        __syncthreads();
    }
    #pragma unroll
    for (int n = 0; n < 2; ++n) {
        int col = w * 32 + n * 16 + l15;
        float bv = bias[col];
        #pragma unroll
        for (int m = 0; m < 4; ++m) {
            #pragma unroll
            for (int r = 0; r < 4; ++r) {
                int grow = row0 + m * 16 + lhi * 4 + r;
                float v = fmaxf(acc[m][n][r] + bv, 0.f);
                Cout[(size_t)grow * 128 + col] = f2bf(v);
            }
        }
    }
}

// ---------------- final FC ----------------
__global__ __launch_bounds__(256) void final_fc(
    const unsigned short* __restrict__ h, const float* __restrict__ fcw,
    const float* __restrict__ fcb, float* __restrict__ out)
{
    int wid  = (int)((blockIdx.x * 256 + threadIdx.x) >> 6);
    int lane = threadIdx.x & 63;
    if (wid >= NN) return;
    float v = bf2f(h[(size_t)wid * 128 + lane]) * fcw[lane]
            + bf2f(h[(size_t)wid * 128 + 64 + lane]) * fcw[64 + lane];
    #pragma unroll
    for (int off = 32; off > 0; off >>= 1) v += __shfl_down(v, off);
    if (lane == 0) out[wid] = v + fcb[0];
}

extern "C" void kernel_launch(void* const* d_in, const int* in_sizes, int n_in,
                              void* d_out, int out_size, void* d_ws, size_t ws_size,
                              hipStream_t stream) {
    const float* x     = (const float*)d_in[0];
    const int*   ei    = (const int*)d_in[1];
    const int*   etype = (const int*)d_in[2];
    const float* W[3]    = {(const float*)d_in[3], (const float*)d_in[6], (const float*)d_in[9]};
    const float* root[3] = {(const float*)d_in[4], (const float*)d_in[7], (const float*)d_in[10]};
    const float* bias[3] = {(const float*)d_in[5], (const float*)d_in[8], (const float*)d_in[11]};
    const float* fcw = (const float*)d_in[12];
    const float* fcb = (const float*)d_in[13];
    const int* src = ei;
    const int* dst = ei + EE;

    char* ws = (char*)d_ws;
    auto alloc = [&](size_t bytes) { char* p = ws; ws += (bytes + 255) & ~(size_t)255; return p; };
    int* deg       = (int*)alloc(NR * sizeof(int));
    int* cursor    = (int*)alloc(NR * sizeof(int));
    int* segStart  = (int*)alloc((NR + 2) * sizeof(int));
    int* bsum      = (int*)alloc(512 * sizeof(int));
    int* ssr       = (int*)alloc(EE * sizeof(int));
    unsigned short* Btg  = (unsigned short*)alloc((size_t)3 * 128 * KK * sizeof(short));
    unsigned short* xbf  = (unsigned short*)alloc((size_t)NPAD * 128 * sizeof(short));
    unsigned short* h1   = (unsigned short*)alloc((size_t)NPAD * 128 * sizeof(short));
    unsigned short* h2   = (unsigned short*)alloc((size_t)NPAD * 128 * sizeof(short));

    // --- graph preprocessing ---
    zero_i32<<<(2 * NR + 255) / 256, 256, 0, stream>>>(deg, 2 * NR);   // deg + cursor contiguous
    count_deg<<<(EE + 255) / 256, 256, 0, stream>>>(dst, etype, deg);
    const int nScanBlk = (NR + 1023) / 1024;   // 391
    scan1<<<nScanBlk, 256, 0, stream>>>(deg, segStart, bsum, NR);
    scan2<<<1, 256, 0, stream>>>(bsum, nScanBlk);
    scan3<<<nScanBlk, 256, 0, stream>>>(segStart, bsum, NR);
    set_last<<<1, 1, 0, stream>>>(segStart);
    scatter_edges<<<(EE + 255) / 256, 256, 0, stream>>>(src, dst, etype, segStart, cursor, ssr);

    // --- input conversion + weight panels ---
    xcvt<<<((NPAD * 128 / 4) + 255) / 256, 256, 0, stream>>>(x, xbf);
    const int btThreads = 128 * KK;
    for (int l = 0; l < 3; ++l)
        build_bt<<<(btThreads + 255) / 256, 256, 0, stream>>>(W[l], root[l], Btg + (size_t)l * 128 * KK);

    const int gemmGrid = NPAD / 64;      // 782
    const unsigned short* hin = xbf;
    unsigned short* houts[3] = {h1, h2, h1};
    for (int l = 0; l < 3; ++l) {
        fused_layer<<<gemmGrid, 256, 0, stream>>>(hin, segStart, ssr,
                                                  Btg + (size_t)l * 128 * KK, bias[l], houts[l]);
        hin = houts[l];
    }

    final_fc<<<(NN * 64 + 255) / 256, 256, 0, stream>>>(h1, fcw, fcb, (float*)d_out);
}

// Round 5
// 431.411 us; speedup vs baseline: 4.2310x; 2.5065x over previous
//
#include <hip/hip_runtime.h>

#define NN 50000
#define NPAD 50048           // padded to multiple of 64 rows
#define EE 800000
#define RR 8
#define NR (NN * RR)         // 400000 (dst,rel) segments
#define KK 1152              // 128 (root) + 8*128 (relations)

typedef __attribute__((ext_vector_type(8))) short bf16x8;
typedef __attribute__((ext_vector_type(4))) float f32x4;

__device__ __forceinline__ unsigned short f2bf(float f) {
    unsigned u = __builtin_bit_cast(unsigned, f);
    u = (u + 0x7FFF + ((u >> 16) & 1)) >> 16;   // RNE
    return (unsigned short)u;
}
__device__ __forceinline__ float bf2f(unsigned short s) {
    return __builtin_bit_cast(float, (unsigned)s << 16);
}

#define GLDS16(g, l) __builtin_amdgcn_global_load_lds( \
    (const __attribute__((address_space(1))) void*)(g), \
    (__attribute__((address_space(3))) void*)(l), 16, 0, 0)

// ---------------- graph preprocessing ----------------
__global__ void zero_i32(int* __restrict__ p, int n) {
    int i = blockIdx.x * blockDim.x + threadIdx.x;
    if (i < n) p[i] = 0;
}

__global__ void count_deg(const int* __restrict__ dst, const int* __restrict__ et,
                          int* __restrict__ deg) {
    int e = blockIdx.x * blockDim.x + threadIdx.x;
    if (e < EE) atomicAdd(&deg[dst[e] * RR + et[e]], 1);
}

// exclusive scan over n ints: 1024 per block
__global__ __launch_bounds__(256) void scan1(const int* __restrict__ in, int* __restrict__ out,
                                             int* __restrict__ bsum, int n) {
    __shared__ int sh[256];
    int t = threadIdx.x;
    int base = blockIdx.x * 1024 + t * 4;
    int v[4]; int s = 0;
    #pragma unroll
    for (int i = 0; i < 4; ++i) { int idx = base + i; v[i] = (idx < n) ? in[idx] : 0; s += v[i]; }
    sh[t] = s; __syncthreads();
    for (int off = 1; off < 256; off <<= 1) {
        int x = (t >= off) ? sh[t - off] : 0; __syncthreads();
        if (t >= off) sh[t] += x; __syncthreads();
    }
    if (t == 255) bsum[blockIdx.x] = sh[255];
    int run = sh[t] - s;
    #pragma unroll
    for (int i = 0; i < 4; ++i) { int idx = base + i; if (idx < n) out[idx] = run; run += v[i]; }
}

__global__ __launch_bounds__(256) void scan2(int* __restrict__ bsum, int nb) {
    __shared__ int sh[256];
    int t = threadIdx.x; int carry = 0;
    for (int base = 0; base < nb; base += 256) {
        int idx = base + t;
        int v = (idx < nb) ? bsum[idx] : 0;
        sh[t] = v; __syncthreads();
        for (int off = 1; off < 256; off <<= 1) {
            int x = (t >= off) ? sh[t - off] : 0; __syncthreads();
            if (t >= off) sh[t] += x; __syncthreads();
        }
        int incl = sh[t];
        int total = sh[255];
        if (idx < nb) bsum[idx] = carry + incl - v;   // exclusive
        carry += total;
        __syncthreads();
    }
}

__global__ __launch_bounds__(256) void scan3(int* __restrict__ out, const int* __restrict__ bsum, int n) {
    int base = blockIdx.x * 1024 + threadIdx.x * 4;
    int add = bsum[blockIdx.x];
    #pragma unroll
    for (int i = 0; i < 4; ++i) { int idx = base + i; if (idx < n) out[idx] += add; }
}

__global__ void set_last(int* __restrict__ segStart) {
    segStart[NR] = EE;
}

__global__ void scatter_edges(const int* __restrict__ src, const int* __restrict__ dst,
                              const int* __restrict__ et, const int* __restrict__ segStart,
                              int* __restrict__ cursor, int* __restrict__ ssr) {
    int e = blockIdx.x * blockDim.x + threadIdx.x;
    if (e >= EE) return;
    int seg = dst[e] * RR + et[e];
    int pos = segStart[seg] + atomicAdd(&cursor[seg], 1);
    ssr[pos] = src[e];
}

// ---------------- x -> bf16 (pad rows zeroed) ----------------
__global__ __launch_bounds__(256) void xcvt(const float* __restrict__ x,
                                            unsigned short* __restrict__ xbf) {
    size_t i = ((size_t)blockIdx.x * 256 + threadIdx.x) * 4;
    if (i >= (size_t)NPAD * 128) return;
    unsigned short o[4];
    if (i < (size_t)NN * 128) {
        float4 v = *reinterpret_cast<const float4*>(x + i);
        o[0] = f2bf(v.x); o[1] = f2bf(v.y); o[2] = f2bf(v.z); o[3] = f2bf(v.w);
    } else {
        o[0] = o[1] = o[2] = o[3] = 0;
    }
    unsigned lo = (unsigned)o[0] | ((unsigned)o[1] << 16);
    unsigned hi = (unsigned)o[2] | ((unsigned)o[3] << 16);
    *reinterpret_cast<uint2*>(xbf + i) = make_uint2(lo, hi);
}

// ---------------- weight layout: Bt[col][k] = Bmat[k][col], bf16 ----------------
__global__ void build_bt(const float* __restrict__ W, const float* __restrict__ root,
                         unsigned short* __restrict__ Bt) {
    int i = blockIdx.x * blockDim.x + threadIdx.x;
    if (i >= 128 * KK) return;
    int col = i / KK, k = i % KK;
    float v;
    if (k < 128) v = root[k * 128 + col];
    else {
        int r = (k - 128) >> 7, kp = (k - 128) & 127;
        v = W[((size_t)r * 128 + kp) * 128 + col];
    }
    Bt[i] = f2bf(v);
}

// ---------------- fused layer: C = relu([hin | seg-means(hin)] @ B + bias) ----------------
// BM=64, 4 waves; K-tiles of 64: kt 0..1 = root cols (global_load_lds from hin);
// kt even>=2: full-row segment walk for relation rr=(kt-2)/2 -> half0 to LDS,
// half1 held in regs; kt odd>=3: dump held half1 regs to LDS.
// Walk: 8 rows x 8 lanes (32B/lane), edge ids shfl-broadcast from a preload.
__global__ __launch_bounds__(256) void fused_layer(
    const unsigned short* __restrict__ hin,   // [NPAD][128] bf16
    const int* __restrict__ segStart,         // [NR+1]
    const int* __restrict__ ssr,              // [EE] sorted src ids
    const unsigned short* __restrict__ Bt,    // [128][1152] (Bt[col][k])
    const float* __restrict__ bias,           // [128]
    unsigned short* __restrict__ Cout)        // [NPAD][128] bf16
{
    __shared__ alignas(16) unsigned short As[2][64 * 64];
    __shared__ alignas(16) unsigned short Bs[2][128 * 64];
    __shared__ int segL[513];
    const int tid = threadIdx.x;
    const int w = tid >> 6, lane = tid & 63;
    const int l15 = lane & 15, lhi = lane >> 4;
    const int wg = lane >> 3;          // row-in-subphase 0..7
    const int g  = lane & 7;           // 32B group within 256B row
    const int row0 = blockIdx.x * 64;

    // segment bounds for this block's 64 nodes (clamped for pad nodes)
    for (int i = tid; i < 513; i += 256) {
        int gi = row0 * 8 + i;
        segL[i] = (gi <= NR) ? segStart[gi] : EE;
    }

    f32x4 acc[4][2];
    #pragma unroll
    for (int m = 0; m < 4; ++m)
        #pragma unroll
        for (int n = 0; n < 2; ++n) acc[m][n] = (f32x4)(0.f);

    unsigned hd[16];   // held half1 (2 subphases x 8 dwords), used by lanes g>=4

    auto stageB = [&](int b, int kt) {
        #pragma unroll
        for (int i = 0; i < 4; ++i) {
            int q = w * 256 + i * 64 + lane;          // chunk id 0..1023
            int col = q >> 3, c = q & 7;
            const unsigned short* gp = Bt + (size_t)col * KK + kt * 64 + ((c ^ (col & 7)) * 8);
            GLDS16(gp, &Bs[b][(w * 256 + i * 64) * 8]);
        }
    };
    auto stageAroot = [&](int b, int kt) {
        #pragma unroll
        for (int i = 0; i < 2; ++i) {
            int q = w * 128 + i * 64 + lane;          // chunk id 0..511
            int row = q >> 3, c = q & 7;
            const unsigned short* gp = hin + (size_t)(row0 + row) * 128 + kt * 64 + ((c ^ (row & 7)) * 8);
            GLDS16(gp, &As[b][(w * 128 + i * 64) * 8]);
        }
    };

    // full-row walk for relation rr: half0 -> As[b], half1 -> hd[]
    auto walkRel = [&](int b, int rr) {
        #pragma unroll
        for (int ph = 0; ph < 2; ++ph) {
            const int ln = w * 16 + ph * 8 + wg;
            const int s0 = segL[ln * 8 + rr], s1 = segL[ln * 8 + rr + 1];
            const int d = s1 - s0;
            float fa[16];
            #pragma unroll
            for (int i = 0; i < 16; ++i) fa[i] = 0.f;
            int ei = s0 + g; if (ei >= EE) ei = EE - 1;
            const int pre = ssr[ei];                  // lane g holds edge s0+g's src
            #pragma unroll
            for (int j = 0; j < 8; ++j) {
                if (j < d) {
                    int sj = __shfl(pre, wg * 8 + j);
                    const unsigned short* p = hin + ((size_t)sj << 7) + g * 16;
                    uint4 u = *reinterpret_cast<const uint4*>(p);
                    uint4 v = *reinterpret_cast<const uint4*>(p + 8);
                    fa[0]  += bf2f((unsigned short)(u.x & 0xFFFF)); fa[1]  += bf2f((unsigned short)(u.x >> 16));
                    fa[2]  += bf2f((unsigned short)(u.y & 0xFFFF)); fa[3]  += bf2f((unsigned short)(u.y >> 16));
                    fa[4]  += bf2f((unsigned short)(u.z & 0xFFFF)); fa[5]  += bf2f((unsigned short)(u.z >> 16));
                    fa[6]  += bf2f((unsigned short)(u.w & 0xFFFF)); fa[7]  += bf2f((unsigned short)(u.w >> 16));
                    fa[8]  += bf2f((unsigned short)(v.x & 0xFFFF)); fa[9]  += bf2f((unsigned short)(v.x >> 16));
                    fa[10] += bf2f((unsigned short)(v.y & 0xFFFF)); fa[11] += bf2f((unsigned short)(v.y >> 16));
                    fa[12] += bf2f((unsigned short)(v.z & 0xFFFF)); fa[13] += bf2f((unsigned short)(v.z >> 16));
                    fa[14] += bf2f((unsigned short)(v.w & 0xFFFF)); fa[15] += bf2f((unsigned short)(v.w >> 16));
                }
            }
            for (int e = s0 + 8; e < s1; ++e) {       // rare deg>8 tail
                int sj = ssr[e];
                const unsigned short* p = hin + ((size_t)sj << 7) + g * 16;
                uint4 u = *reinterpret_cast<const uint4*>(p);
                uint4 v = *reinterpret_cast<const uint4*>(p + 8);
                fa[0]  += bf2f((unsigned short)(u.x & 0xFFFF)); fa[1]  += bf2f((unsigned short)(u.x >> 16));
                fa[2]  += bf2f((unsigned short)(u.y & 0xFFFF)); fa[3]  += bf2f((unsigned short)(u.y >> 16));
                fa[4]  += bf2f((unsigned short)(u.z & 0xFFFF)); fa[5]  += bf2f((unsigned short)(u.z >> 16));
                fa[6]  += bf2f((unsigned short)(u.w & 0xFFFF)); fa[7]  += bf2f((unsigned short)(u.w >> 16));
                fa[8]  += bf2f((unsigned short)(v.x & 0xFFFF)); fa[9]  += bf2f((unsigned short)(v.x >> 16));
                fa[10] += bf2f((unsigned short)(v.y & 0xFFFF)); fa[11] += bf2f((unsigned short)(v.y >> 16));
                fa[12] += bf2f((unsigned short)(v.z & 0xFFFF)); fa[13] += bf2f((unsigned short)(v.z >> 16));
                fa[14] += bf2f((unsigned short)(v.w & 0xFFFF)); fa[15] += bf2f((unsigned short)(v.w >> 16));
            }
            const float inv = (d > 0) ? 1.f / (float)d : 0.f;
            unsigned dw[8];
            #pragma unroll
            for (int j = 0; j < 8; ++j)
                dw[j] = (unsigned)f2bf(fa[2 * j] * inv) | ((unsigned)f2bf(fa[2 * j + 1] * inv) << 16);
            if (g < 4) {   // half0: lane covers within-tile chunks 2g, 2g+1
                int c0 = (2 * g)     ^ (ln & 7);
                int c1 = (2 * g + 1) ^ (ln & 7);
                *reinterpret_cast<uint4*>(&As[b][ln * 64 + c0 * 8]) = make_uint4(dw[0], dw[1], dw[2], dw[3]);
                *reinterpret_cast<uint4*>(&As[b][ln * 64 + c1 * 8]) = make_uint4(dw[4], dw[5], dw[6], dw[7]);
            }
            #pragma unroll
            for (int j = 0; j < 8; ++j) hd[ph * 8 + j] = dw[j];
        }
    };

    auto dumpRel = [&](int b) {
        if (g >= 4) {   // half1: lane covers within-tile chunks 2(g-4), 2(g-4)+1
            #pragma unroll
            for (int ph = 0; ph < 2; ++ph) {
                const int ln = w * 16 + ph * 8 + wg;
                int gg = g - 4;
                int c0 = (2 * gg)     ^ (ln & 7);
                int c1 = (2 * gg + 1) ^ (ln & 7);
                *reinterpret_cast<uint4*>(&As[b][ln * 64 + c0 * 8]) =
                    make_uint4(hd[ph * 8 + 0], hd[ph * 8 + 1], hd[ph * 8 + 2], hd[ph * 8 + 3]);
                *reinterpret_cast<uint4*>(&As[b][ln * 64 + c1 * 8]) =
                    make_uint4(hd[ph * 8 + 4], hd[ph * 8 + 5], hd[ph * 8 + 6], hd[ph * 8 + 7]);
            }
        }
    };

    __syncthreads();   // segL ready
    stageB(0, 0);
    stageAroot(0, 0);
    __syncthreads();
    for (int kt = 0; kt < KK / 64; ++kt) {
        const int cur = kt & 1;
        if (kt < KK / 64 - 1) {
            stageB(cur ^ 1, kt + 1);
            if (kt + 1 == 1)              stageAroot(cur ^ 1, 1);
            else if (((kt + 1) & 1) == 0) walkRel(cur ^ 1, (kt + 1 - 2) >> 1);
            else                          dumpRel(cur ^ 1);
        }
        #pragma unroll
        for (int j = 0; j < 2; ++j) {
            const int clog = j * 4 + lhi;
            bf16x8 af[4], bfr[2];
            #pragma unroll
            for (int m = 0; m < 4; ++m) {
                int row = m * 16 + l15;
                int ch = clog ^ (row & 7);
                af[m] = *reinterpret_cast<const bf16x8*>(&As[cur][row * 64 + ch * 8]);
            }
            #pragma unroll
            for (int n = 0; n < 2; ++n) {
                int col = w * 32 + n * 16 + l15;
                int ch = clog ^ (col & 7);
                bfr[n] = *reinterpret_cast<const bf16x8*>(&Bs[cur][col * 64 + ch * 8]);
            }
            #pragma unroll
            for (int m = 0; m < 4; ++m)
                #pragma unroll
                for (int n = 0; n < 2; ++n)
                    acc[m][n] = __builtin_amdgcn_mfma_f32_16x16x32_bf16(af[m], bfr[n], acc[m][n], 0, 0, 0);
        }
        __syncthreads();   // drains vmcnt+lgkm: next tile staged, buffers swap
    }
    #pragma unroll
    for (int n = 0; n < 2; ++n) {
        int col = w * 32 + n * 16 + l15;
        float bv = bias[col];
        #pragma unroll
        for (int m = 0; m < 4; ++m) {
            #pragma unroll
            for (int r = 0; r < 4; ++r) {
                int grow = row0 + m * 16 + lhi * 4 + r;
                float v = fmaxf(acc[m][n][r] + bv, 0.f);
                Cout[(size_t)grow * 128 + col] = f2bf(v);
            }
        }
    }
}

// ---------------- final FC ----------------
__global__ __launch_bounds__(256) void final_fc(
    const unsigned short* __restrict__ h, const float* __restrict__ fcw,
    const float* __restrict__ fcb, float* __restrict__ out)
{
    int wid  = (int)((blockIdx.x * 256 + threadIdx.x) >> 6);
    int lane = threadIdx.x & 63;
    if (wid >= NN) return;
    float v = bf2f(h[(size_t)wid * 128 + lane]) * fcw[lane]
            + bf2f(h[(size_t)wid * 128 + 64 + lane]) * fcw[64 + lane];
    #pragma unroll
    for (int off = 32; off > 0; off >>= 1) v += __shfl_down(v, off);
    if (lane == 0) out[wid] = v + fcb[0];
}

extern "C" void kernel_launch(void* const* d_in, const int* in_sizes, int n_in,
                              void* d_out, int out_size, void* d_ws, size_t ws_size,
                              hipStream_t stream) {
    const float* x     = (const float*)d_in[0];
    const int*   ei    = (const int*)d_in[1];
    const int*   etype = (const int*)d_in[2];
    const float* W[3]    = {(const float*)d_in[3], (const float*)d_in[6], (const float*)d_in[9]};
    const float* root[3] = {(const float*)d_in[4], (const float*)d_in[7], (const float*)d_in[10]};
    const float* bias[3] = {(const float*)d_in[5], (const float*)d_in[8], (const float*)d_in[11]};
    const float* fcw = (const float*)d_in[12];
    const float* fcb = (const float*)d_in[13];
    const int* src = ei;
    const int* dst = ei + EE;

    char* ws = (char*)d_ws;
    auto alloc = [&](size_t bytes) { char* p = ws; ws += (bytes + 255) & ~(size_t)255; return p; };
    int* deg       = (int*)alloc(NR * sizeof(int));
    int* cursor    = (int*)alloc(NR * sizeof(int));
    int* segStart  = (int*)alloc((NR + 2) * sizeof(int));
    int* bsum      = (int*)alloc(512 * sizeof(int));
    int* ssr       = (int*)alloc(EE * sizeof(int));
    unsigned short* Btg  = (unsigned short*)alloc((size_t)3 * 128 * KK * sizeof(short));
    unsigned short* xbf  = (unsigned short*)alloc((size_t)NPAD * 128 * sizeof(short));
    unsigned short* h1   = (unsigned short*)alloc((size_t)NPAD * 128 * sizeof(short));
    unsigned short* h2   = (unsigned short*)alloc((size_t)NPAD * 128 * sizeof(short));

    // --- graph preprocessing ---
    zero_i32<<<(2 * NR + 255) / 256, 256, 0, stream>>>(deg, 2 * NR);   // deg + cursor contiguous
    count_deg<<<(EE + 255) / 256, 256, 0, stream>>>(dst, etype, deg);
    const int nScanBlk = (NR + 1023) / 1024;   // 391
    scan1<<<nScanBlk, 256, 0, stream>>>(deg, segStart, bsum, NR);
    scan2<<<1, 256, 0, stream>>>(bsum, nScanBlk);
    scan3<<<nScanBlk, 256, 0, stream>>>(segStart, bsum, NR);
    set_last<<<1, 1, 0, stream>>>(segStart);
    scatter_edges<<<(EE + 255) / 256, 256, 0, stream>>>(src, dst, etype, segStart, cursor, ssr);

    // --- input conversion + weight panels ---
    xcvt<<<((NPAD * 128 / 4) + 255) / 256, 256, 0, stream>>>(x, xbf);
    const int btThreads = 128 * KK;
    for (int l = 0; l < 3; ++l)
        build_bt<<<(btThreads + 255) / 256, 256, 0, stream>>>(W[l], root[l], Btg + (size_t)l * 128 * KK);

    const int gemmGrid = NPAD / 64;      // 782
    const unsigned short* hin = xbf;
    unsigned short* houts[3] = {h1, h2, h1};
    for (int l = 0; l < 3; ++l) {
        fused_layer<<<gemmGrid, 256, 0, stream>>>(hin, segStart, ssr,
                                                  Btg + (size_t)l * 128 * KK, bias[l], houts[l]);
        hin = houts[l];
    }

    final_fc<<<(NN * 64 + 255) / 256, 256, 0, stream>>>(h1, fcw, fcb, (float*)d_out);
}

// Round 6
// 354.347 us; speedup vs baseline: 5.1512x; 1.2175x over previous
//
#include <hip/hip_runtime.h>

#define NN 50000
#define NPAD 50048           // padded to multiple of 64 rows
#define EE 800000
#define RR 8
#define NR (NN * RR)         // 400000 (dst,rel) segments
#define KK 1152              // 128 (root) + 8*128 (relations)

typedef __attribute__((ext_vector_type(8))) short bf16x8;
typedef __attribute__((ext_vector_type(4))) float f32x4;

__device__ __forceinline__ unsigned short f2bf(float f) {
    unsigned u = __builtin_bit_cast(unsigned, f);
    u = (u + 0x7FFF + ((u >> 16) & 1)) >> 16;   // RNE
    return (unsigned short)u;
}
__device__ __forceinline__ float bf2f(unsigned short s) {
    return __builtin_bit_cast(float, (unsigned)s << 16);
}

#define GLDS16(g, l) __builtin_amdgcn_global_load_lds( \
    (const __attribute__((address_space(1))) void*)(g), \
    (__attribute__((address_space(3))) void*)(l), 16, 0, 0)

// ---------------- graph preprocessing ----------------
__global__ void zero_i32(int* __restrict__ p, int n) {
    int i = blockIdx.x * blockDim.x + threadIdx.x;
    if (i < n) p[i] = 0;
}

__global__ void count_deg(const int* __restrict__ dst, const int* __restrict__ et,
                          int* __restrict__ deg) {
    int e = blockIdx.x * blockDim.x + threadIdx.x;
    if (e < EE) atomicAdd(&deg[dst[e] * RR + et[e]], 1);
}

// exclusive scan over n ints: 1024 per block
__global__ __launch_bounds__(256) void scan1(const int* __restrict__ in, int* __restrict__ out,
                                             int* __restrict__ bsum, int n) {
    __shared__ int sh[256];
    int t = threadIdx.x;
    int base = blockIdx.x * 1024 + t * 4;
    int v[4]; int s = 0;
    #pragma unroll
    for (int i = 0; i < 4; ++i) { int idx = base + i; v[i] = (idx < n) ? in[idx] : 0; s += v[i]; }
    sh[t] = s; __syncthreads();
    for (int off = 1; off < 256; off <<= 1) {
        int x = (t >= off) ? sh[t - off] : 0; __syncthreads();
        if (t >= off) sh[t] += x; __syncthreads();
    }
    if (t == 255) bsum[blockIdx.x] = sh[255];
    int run = sh[t] - s;
    #pragma unroll
    for (int i = 0; i < 4; ++i) { int idx = base + i; if (idx < n) out[idx] = run; run += v[i]; }
}

__global__ __launch_bounds__(256) void scan2(int* __restrict__ bsum, int nb) {
    __shared__ int sh[256];
    int t = threadIdx.x; int carry = 0;
    for (int base = 0; base < nb; base += 256) {
        int idx = base + t;
        int v = (idx < nb) ? bsum[idx] : 0;
        sh[t] = v; __syncthreads();
        for (int off = 1; off < 256; off <<= 1) {
            int x = (t >= off) ? sh[t - off] : 0; __syncthreads();
            if (t >= off) sh[t] += x; __syncthreads();
        }
        int incl = sh[t];
        int total = sh[255];
        if (idx < nb) bsum[idx] = carry + incl - v;   // exclusive
        carry += total;
        __syncthreads();
    }
}

__global__ __launch_bounds__(256) void scan3(int* __restrict__ out, const int* __restrict__ bsum, int n) {
    int base = blockIdx.x * 1024 + threadIdx.x * 4;
    int add = bsum[blockIdx.x];
    #pragma unroll
    for (int i = 0; i < 4; ++i) { int idx = base + i; if (idx < n) out[idx] += add; }
}

__global__ void set_last(int* __restrict__ segStart) {
    segStart[NR] = EE;
}

__global__ void scatter_edges(const int* __restrict__ src, const int* __restrict__ dst,
                              const int* __restrict__ et, const int* __restrict__ segStart,
                              int* __restrict__ cursor, int* __restrict__ ssr) {
    int e = blockIdx.x * blockDim.x + threadIdx.x;
    if (e >= EE) return;
    int seg = dst[e] * RR + et[e];
    int pos = segStart[seg] + atomicAdd(&cursor[seg], 1);
    ssr[pos] = src[e];
}

// ---------------- x -> bf16 (pad rows zeroed) ----------------
__global__ __launch_bounds__(256) void xcvt(const float* __restrict__ x,
                                            unsigned short* __restrict__ xbf) {
    size_t i = ((size_t)blockIdx.x * 256 + threadIdx.x) * 4;
    if (i >= (size_t)NPAD * 128) return;
    unsigned short o[4];
    if (i < (size_t)NN * 128) {
        float4 v = *reinterpret_cast<const float4*>(x + i);
        o[0] = f2bf(v.x); o[1] = f2bf(v.y); o[2] = f2bf(v.z); o[3] = f2bf(v.w);
    } else {
        o[0] = o[1] = o[2] = o[3] = 0;
    }
    unsigned lo = (unsigned)o[0] | ((unsigned)o[1] << 16);
    unsigned hi = (unsigned)o[2] | ((unsigned)o[3] << 16);
    *reinterpret_cast<uint2*>(xbf + i) = make_uint2(lo, hi);
}

// ---------------- weight layout: Bt[col][k] = Bmat[k][col], bf16 ----------------
__global__ void build_bt(const float* __restrict__ W, const float* __restrict__ root,
                         unsigned short* __restrict__ Bt) {
    int i = blockIdx.x * blockDim.x + threadIdx.x;
    if (i >= 128 * KK) return;
    int col = i / KK, k = i % KK;
    float v;
    if (k < 128) v = root[k * 128 + col];
    else {
        int r = (k - 128) >> 7, kp = (k - 128) & 127;
        v = W[((size_t)r * 128 + kp) * 128 + col];
    }
    Bt[i] = f2bf(v);
}

// ---------------- fused layer: C = relu([hin | seg-means(hin)] @ B + bias) ----------------
// BM=64, 4 waves; K-tiles of 64: kt 0..1 = root cols (global_load_lds from hin);
// kt even>=2: full-row segment walk for relation rr=(kt-2)/2 -> half0 to LDS,
// half1 held in regs; kt odd>=3: dump held half1 regs to LDS.
// Walk: 8 rows x 8 lanes (32B/lane); all 16 gathers issued via landing arrays
// (masked-address, unconditional) so one vmcnt round covers the segment.
__global__ __launch_bounds__(256, 1) void fused_layer(
    const unsigned short* __restrict__ hin,   // [NPAD][128] bf16
    const int* __restrict__ segStart,         // [NR+1]
    const int* __restrict__ ssr,              // [EE] sorted src ids
    const unsigned short* __restrict__ Bt,    // [128][1152] (Bt[col][k])
    const float* __restrict__ bias,           // [128]
    unsigned short* __restrict__ Cout)        // [NPAD][128] bf16
{
    __shared__ alignas(16) unsigned short As[2][64 * 64];
    __shared__ alignas(16) unsigned short Bs[2][128 * 64];
    __shared__ int segL[513];
    const int tid = threadIdx.x;
    const int w = tid >> 6, lane = tid & 63;
    const int l15 = lane & 15, lhi = lane >> 4;
    const int wg = lane >> 3;          // row-in-subphase 0..7
    const int g  = lane & 7;           // 32B group within 256B row
    const int row0 = blockIdx.x * 64;

    // segment bounds for this block's 64 nodes (clamped for pad nodes)
    for (int i = tid; i < 513; i += 256) {
        int gi = row0 * 8 + i;
        segL[i] = (gi <= NR) ? segStart[gi] : EE;
    }

    f32x4 acc[4][2];
    #pragma unroll
    for (int m = 0; m < 4; ++m)
        #pragma unroll
        for (int n = 0; n < 2; ++n) acc[m][n] = (f32x4)(0.f);

    unsigned hd[16];   // held half1 (2 subphases x 8 dwords), used by lanes g>=4
    int pre0, pre1;    // preloaded ssr for current relation (ph0/ph1 rows)

    auto stageB = [&](int b, int kt) {
        #pragma unroll
        for (int i = 0; i < 4; ++i) {
            int q = w * 256 + i * 64 + lane;          // chunk id 0..1023
            int col = q >> 3, c = q & 7;
            const unsigned short* gp = Bt + (size_t)col * KK + kt * 64 + ((c ^ (col & 7)) * 8);
            GLDS16(gp, &Bs[b][(w * 256 + i * 64) * 8]);
        }
    };
    auto stageAroot = [&](int b, int kt) {
        #pragma unroll
        for (int i = 0; i < 2; ++i) {
            int q = w * 128 + i * 64 + lane;          // chunk id 0..511
            int row = q >> 3, c = q & 7;
            const unsigned short* gp = hin + (size_t)(row0 + row) * 128 + kt * 64 + ((c ^ (row & 7)) * 8);
            GLDS16(gp, &As[b][(w * 128 + i * 64) * 8]);
        }
    };

    // full-row walk for relation rr: half0 -> As[b], half1 -> hd[]
    auto walkRel = [&](int b, int rr) {
        // issue next relation's ssr preload early (hidden under this walk)
        const int nx = (rr + 1 < RR) ? rr + 1 : rr;
        int en0 = segL[(w * 16 + wg) * 8 + nx] + g;     if (en0 >= EE) en0 = EE - 1;
        int en1 = segL[(w * 16 + 8 + wg) * 8 + nx] + g; if (en1 >= EE) en1 = EE - 1;
        const int pn0 = ssr[en0];
        const int pn1 = ssr[en1];
        const int preCur[2] = {pre0, pre1};
        #pragma unroll
        for (int ph = 0; ph < 2; ++ph) {
            const int ln = w * 16 + ph * 8 + wg;
            const int s0 = segL[ln * 8 + rr], s1 = segL[ln * 8 + rr + 1];
            const int d = s1 - s0;
            const int pre = preCur[ph];
            // landing arrays: all 16 loads issue back-to-back (masked address)
            uint4 u[8], v[8];
            #pragma unroll
            for (int j = 0; j < 8; ++j) {
                int sj = __shfl(pre, wg * 8 + j);
                const unsigned short* p = hin + ((size_t)(j < d ? sj : 0) << 7) + g * 16;
                u[j] = *reinterpret_cast<const uint4*>(p);
                v[j] = *reinterpret_cast<const uint4*>(p + 8);
            }
            float fa[16];
            #pragma unroll
            for (int i = 0; i < 16; ++i) fa[i] = 0.f;
            #pragma unroll
            for (int j = 0; j < 8; ++j) {
                if (j < d) {
                    fa[0]  += bf2f((unsigned short)(u[j].x & 0xFFFF)); fa[1]  += bf2f((unsigned short)(u[j].x >> 16));
                    fa[2]  += bf2f((unsigned short)(u[j].y & 0xFFFF)); fa[3]  += bf2f((unsigned short)(u[j].y >> 16));
                    fa[4]  += bf2f((unsigned short)(u[j].z & 0xFFFF)); fa[5]  += bf2f((unsigned short)(u[j].z >> 16));
                    fa[6]  += bf2f((unsigned short)(u[j].w & 0xFFFF)); fa[7]  += bf2f((unsigned short)(u[j].w >> 16));
                    fa[8]  += bf2f((unsigned short)(v[j].x & 0xFFFF)); fa[9]  += bf2f((unsigned short)(v[j].x >> 16));
                    fa[10] += bf2f((unsigned short)(v[j].y & 0xFFFF)); fa[11] += bf2f((unsigned short)(v[j].y >> 16));
                    fa[12] += bf2f((unsigned short)(v[j].z & 0xFFFF)); fa[13] += bf2f((unsigned short)(v[j].z >> 16));
                    fa[14] += bf2f((unsigned short)(v[j].w & 0xFFFF)); fa[15] += bf2f((unsigned short)(v[j].w >> 16));
                }
            }
            for (int e = s0 + 8; e < s1; ++e) {       // rare deg>8 tail
                int sj = ssr[e];
                const unsigned short* p = hin + ((size_t)sj << 7) + g * 16;
                uint4 uu = *reinterpret_cast<const uint4*>(p);
                uint4 vv = *reinterpret_cast<const uint4*>(p + 8);
                fa[0]  += bf2f((unsigned short)(uu.x & 0xFFFF)); fa[1]  += bf2f((unsigned short)(uu.x >> 16));
                fa[2]  += bf2f((unsigned short)(uu.y & 0xFFFF)); fa[3]  += bf2f((unsigned short)(uu.y >> 16));
                fa[4]  += bf2f((unsigned short)(uu.z & 0xFFFF)); fa[5]  += bf2f((unsigned short)(uu.z >> 16));
                fa[6]  += bf2f((unsigned short)(uu.w & 0xFFFF)); fa[7]  += bf2f((unsigned short)(uu.w >> 16));
                fa[8]  += bf2f((unsigned short)(vv.x & 0xFFFF)); fa[9]  += bf2f((unsigned short)(vv.x >> 16));
                fa[10] += bf2f((unsigned short)(vv.y & 0xFFFF)); fa[11] += bf2f((unsigned short)(vv.y >> 16));
                fa[12] += bf2f((unsigned short)(vv.z & 0xFFFF)); fa[13] += bf2f((unsigned short)(vv.z >> 16));
                fa[14] += bf2f((unsigned short)(vv.w & 0xFFFF)); fa[15] += bf2f((unsigned short)(vv.w >> 16));
            }
            const float inv = (d > 0) ? 1.f / (float)d : 0.f;
            unsigned dw[8];
            #pragma unroll
            for (int j = 0; j < 8; ++j)
                dw[j] = (unsigned)f2bf(fa[2 * j] * inv) | ((unsigned)f2bf(fa[2 * j + 1] * inv) << 16);
            if (g < 4) {   // half0: lane covers within-tile chunks 2g, 2g+1
                int c0 = (2 * g)     ^ (ln & 7);
                int c1 = (2 * g + 1) ^ (ln & 7);
                *reinterpret_cast<uint4*>(&As[b][ln * 64 + c0 * 8]) = make_uint4(dw[0], dw[1], dw[2], dw[3]);
                *reinterpret_cast<uint4*>(&As[b][ln * 64 + c1 * 8]) = make_uint4(dw[4], dw[5], dw[6], dw[7]);
            }
            #pragma unroll
            for (int j = 0; j < 8; ++j) hd[ph * 8 + j] = dw[j];
        }
        pre0 = pn0; pre1 = pn1;
    };

    auto dumpRel = [&](int b) {
        if (g >= 4) {   // half1: lane covers within-tile chunks 2(g-4), 2(g-4)+1
            #pragma unroll
            for (int ph = 0; ph < 2; ++ph) {
                const int ln = w * 16 + ph * 8 + wg;
                int gg = g - 4;
                int c0 = (2 * gg)     ^ (ln & 7);
                int c1 = (2 * gg + 1) ^ (ln & 7);
                *reinterpret_cast<uint4*>(&As[b][ln * 64 + c0 * 8]) =
                    make_uint4(hd[ph * 8 + 0], hd[ph * 8 + 1], hd[ph * 8 + 2], hd[ph * 8 + 3]);
                *reinterpret_cast<uint4*>(&As[b][ln * 64 + c1 * 8]) =
                    make_uint4(hd[ph * 8 + 4], hd[ph * 8 + 5], hd[ph * 8 + 6], hd[ph * 8 + 7]);
            }
        }
    };

    __syncthreads();   // segL ready
    {  // preload ssr for relation 0
        int e0 = segL[(w * 16 + wg) * 8] + g;     if (e0 >= EE) e0 = EE - 1;
        int e1 = segL[(w * 16 + 8 + wg) * 8] + g; if (e1 >= EE) e1 = EE - 1;
        pre0 = ssr[e0]; pre1 = ssr[e1];
    }
    stageB(0, 0);
    stageAroot(0, 0);
    __syncthreads();
    for (int kt = 0; kt < KK / 64; ++kt) {
        const int cur = kt & 1;
        if (kt < KK / 64 - 1) {
            stageB(cur ^ 1, kt + 1);
            if (kt + 1 == 1)              stageAroot(cur ^ 1, 1);
            else if (((kt + 1) & 1) == 0) walkRel(cur ^ 1, (kt + 1 - 2) >> 1);
            else                          dumpRel(cur ^ 1);
        }
        #pragma unroll
        for (int j = 0; j < 2; ++j) {
            const int clog = j * 4 + lhi;
            bf16x8 af[4], bfr[2];
            #pragma unroll
            for (int m = 0; m < 4; ++m) {
                int row = m * 16 + l15;
                int ch = clog ^ (row & 7);
                af[m] = *reinterpret_cast<const bf16x8*>(&As[cur][row * 64 + ch * 8]);
            }
            #pragma unroll
            for (int n = 0; n < 2; ++n) {
                int col = w * 32 + n * 16 + l15;
                int ch = clog ^ (col & 7);
                bfr[n] = *reinterpret_cast<const bf16x8*>(&Bs[cur][col * 64 + ch * 8]);
            }
            #pragma unroll
            for (int m = 0; m < 4; ++m)
                #pragma unroll
                for (int n = 0; n < 2; ++n)
                    acc[m][n] = __builtin_amdgcn_mfma_f32_16x16x32_bf16(af[m], bfr[n], acc[m][n], 0, 0, 0);
        }
        __syncthreads();   // drains vmcnt+lgkm: next tile staged, buffers swap
    }
    #pragma unroll
    for (int n = 0; n < 2; ++n) {
        int col = w * 32 + n * 16 + l15;
        float bv = bias[col];
        #pragma unroll
        for (int m = 0; m < 4; ++m) {
            #pragma unroll
            for (int r = 0; r < 4; ++r) {
                int grow = row0 + m * 16 + lhi * 4 + r;
                float v = fmaxf(acc[m][n][r] + bv, 0.f);
                Cout[(size_t)grow * 128 + col] = f2bf(v);
            }
        }
    }
}

// ---------------- final FC ----------------
__global__ __launch_bounds__(256) void final_fc(
    const unsigned short* __restrict__ h, const float* __restrict__ fcw,
    const float* __restrict__ fcb, float* __restrict__ out)
{
    int wid  = (int)((blockIdx.x * 256 + threadIdx.x) >> 6);
    int lane = threadIdx.x & 63;
    if (wid >= NN) return;
    float v = bf2f(h[(size_t)wid * 128 + lane]) * fcw[lane]
            + bf2f(h[(size_t)wid * 128 + 64 + lane]) * fcw[64 + lane];
    #pragma unroll
    for (int off = 32; off > 0; off >>= 1) v += __shfl_down(v, off);
    if (lane == 0) out[wid] = v + fcb[0];
}

extern "C" void kernel_launch(void* const* d_in, const int* in_sizes, int n_in,
                              void* d_out, int out_size, void* d_ws, size_t ws_size,
                              hipStream_t stream) {
    const float* x     = (const float*)d_in[0];
    const int*   ei    = (const int*)d_in[1];
    const int*   etype = (const int*)d_in[2];
    const float* W[3]    = {(const float*)d_in[3], (const float*)d_in[6], (const float*)d_in[9]};
    const float* root[3] = {(const float*)d_in[4], (const float*)d_in[7], (const float*)d_in[10]};
    const float* bias[3] = {(const float*)d_in[5], (const float*)d_in[8], (const float*)d_in[11]};
    const float* fcw = (const float*)d_in[12];
    const float* fcb = (const float*)d_in[13];
    const int* src = ei;
    const int* dst = ei + EE;

    char* ws = (char*)d_ws;
    auto alloc = [&](size_t bytes) { char* p = ws; ws += (bytes + 255) & ~(size_t)255; return p; };
    int* deg       = (int*)alloc(NR * sizeof(int));
    int* cursor    = (int*)alloc(NR * sizeof(int));
    int* segStart  = (int*)alloc((NR + 2) * sizeof(int));
    int* bsum      = (int*)alloc(512 * sizeof(int));
    int* ssr       = (int*)alloc(EE * sizeof(int));
    unsigned short* Btg  = (unsigned short*)alloc((size_t)3 * 128 * KK * sizeof(short));
    unsigned short* xbf  = (unsigned short*)alloc((size_t)NPAD * 128 * sizeof(short));
    unsigned short* h1   = (unsigned short*)alloc((size_t)NPAD * 128 * sizeof(short));
    unsigned short* h2   = (unsigned short*)alloc((size_t)NPAD * 128 * sizeof(short));

    // --- graph preprocessing ---
    zero_i32<<<(2 * NR + 255) / 256, 256, 0, stream>>>(deg, 2 * NR);   // deg + cursor contiguous
    count_deg<<<(EE + 255) / 256, 256, 0, stream>>>(dst, etype, deg);
    const int nScanBlk = (NR + 1023) / 1024;   // 391
    scan1<<<nScanBlk, 256, 0, stream>>>(deg, segStart, bsum, NR);
    scan2<<<1, 256, 0, stream>>>(bsum, nScanBlk);
    scan3<<<nScanBlk, 256, 0, stream>>>(segStart, bsum, NR);
    set_last<<<1, 1, 0, stream>>>(segStart);
    scatter_edges<<<(EE + 255) / 256, 256, 0, stream>>>(src, dst, etype, segStart, cursor, ssr);

    // --- input conversion + weight panels ---
    xcvt<<<((NPAD * 128 / 4) + 255) / 256, 256, 0, stream>>>(x, xbf);
    const int btThreads = 128 * KK;
    for (int l = 0; l < 3; ++l)
        build_bt<<<(btThreads + 255) / 256, 256, 0, stream>>>(W[l], root[l], Btg + (size_t)l * 128 * KK);

    const int gemmGrid = NPAD / 64;      // 782
    const unsigned short* hin = xbf;
    unsigned short* houts[3] = {h1, h2, h1};
    for (int l = 0; l < 3; ++l) {
        fused_layer<<<gemmGrid, 256, 0, stream>>>(hin, segStart, ssr,
                                                  Btg + (size_t)l * 128 * KK, bias[l], houts[l]);
        hin = houts[l];
    }

    final_fc<<<(NN * 64 + 255) / 256, 256, 0, stream>>>(h1, fcw, fcb, (float*)d_out);
}